// Round 1
// baseline (47.202 us; speedup 1.0000x reference)
//
#include <hip/hip_runtime.h>

// JSD(P, W) for shape (8192, 4096) fp32:
//   M = 0.5*(W+P)
//   result = 0.5 * ( sum_{w>0,m>0} w*log2(w/m) + sum_{p>0,m>0} p*log2(p/m) ) / 8192
//
// Memory-bound streaming reduction: 268 MB read -> one scalar.
// Stage 1: grid-stride float4 loads, per-thread float partials, wave+block reduce,
//          per-block partial to d_ws.
// Stage 2: single block reduces the partials in double, writes scaled scalar.

__device__ __forceinline__ float jsd_term(float p, float w) {
    float m  = 0.5f * (w + p);
    float lm = __log2f(m);           // -inf when m==0, discarded by selects below
    float tw = (w > 0.0f && m > 0.0f) ? w * (__log2f(w) - lm) : 0.0f;
    float tp = (p > 0.0f && m > 0.0f) ? p * (__log2f(p) - lm) : 0.0f;
    return tw + tp;
}

__global__ void __launch_bounds__(256) jsd_partial_kernel(
    const float4* __restrict__ P4, const float4* __restrict__ W4,
    float* __restrict__ partials, int n4) {
    float acc = 0.0f;
    int idx    = blockIdx.x * blockDim.x + threadIdx.x;
    int stride = gridDim.x * blockDim.x;
    for (int i = idx; i < n4; i += stride) {
        float4 p = P4[i];
        float4 w = W4[i];
        acc += jsd_term(p.x, w.x);
        acc += jsd_term(p.y, w.y);
        acc += jsd_term(p.z, w.z);
        acc += jsd_term(p.w, w.w);
    }
    // wave (64-lane) reduction
    #pragma unroll
    for (int off = 32; off > 0; off >>= 1)
        acc += __shfl_down(acc, off, 64);
    __shared__ float smem[4];  // 256 threads = 4 waves
    int wave = threadIdx.x >> 6;
    if ((threadIdx.x & 63) == 0) smem[wave] = acc;
    __syncthreads();
    if (threadIdx.x == 0)
        partials[blockIdx.x] = smem[0] + smem[1] + smem[2] + smem[3];
}

__global__ void __launch_bounds__(256) jsd_finish_kernel(
    const float* __restrict__ partials, int n, float* __restrict__ out) {
    double acc = 0.0;
    for (int i = threadIdx.x; i < n; i += blockDim.x)
        acc += (double)partials[i];
    #pragma unroll
    for (int off = 32; off > 0; off >>= 1)
        acc += __shfl_down(acc, off, 64);
    __shared__ double smem[4];
    int wave = threadIdx.x >> 6;
    if ((threadIdx.x & 63) == 0) smem[wave] = acc;
    __syncthreads();
    if (threadIdx.x == 0) {
        double total = smem[0] + smem[1] + smem[2] + smem[3];
        out[0] = (float)(total * (0.5 / 8192.0));
    }
}

extern "C" void kernel_launch(void* const* d_in, const int* in_sizes, int n_in,
                              void* d_out, int out_size, void* d_ws, size_t ws_size,
                              hipStream_t stream) {
    const float* P = (const float*)d_in[0];
    const float* W = (const float*)d_in[1];
    float* out = (float*)d_out;
    float* partials = (float*)d_ws;

    const long long n = (long long)in_sizes[0];    // 8192*4096 = 33554432
    const int n4 = (int)(n / 4);                   // divisible

    const int threads = 256;
    const int blocks  = 2048;                       // 256 CU * 8 blocks

    jsd_partial_kernel<<<blocks, threads, 0, stream>>>(
        (const float4*)P, (const float4*)W, partials, n4);
    jsd_finish_kernel<<<1, threads, 0, stream>>>(partials, blocks, out);
}